// Round 1
// baseline (786.745 us; speedup 1.0000x reference)
//
#include <hip/hip_runtime.h>
#include <hip/hip_fp16.h>

#define BSZ 4
#define CCH 8
#define NN  8192
#define KK  16
#define DD  64
#define HHD 4
#define FFD 256
#define NT  (BSZ*NN)   // 32768 tokens

// ---------------- workspace layout (in floats) ----------------
#define WS_X0   0
#define WS_XN   (WS_X0 + NT*CCH)          // 262144
#define WS_IDX  (WS_XN + NT*CCH)          // int region, NT*KK ints
#define WS_M    (WS_IDX + NT*KK)          // 256 floats
#define WS_EVO  (WS_M + 256)              // 2048 floats
#define WS_H1   (WS_EVO + 2048)           // NT*64 floats

// ---------------- weight fusion (tiny, 1 block) ----------------
__global__ __launch_bounds__(256) void k_fusew(const float* __restrict__ Wemb,
                                               const float* __restrict__ Wqkv,
                                               const float* __restrict__ Wo,
                                               float* __restrict__ Mout,
                                               float* __restrict__ Wevo) {
  __shared__ float eq[512], ek[512], ev[512];
  int tid = threadIdx.x;
  for (int i = tid; i < 1536; i += 256) {
    int w = i >> 9;           // 0=q,1=k,2=v
    int r = i & 511;          // c*64+d
    int c = r >> 6, d = r & 63;
    float s = 0.f;
    for (int e = 0; e < 64; ++e) s = fmaf(Wemb[c*64+e], Wqkv[w*4096 + e*64 + d], s);
    float* dst = (w == 0) ? eq : ((w == 1) ? ek : ev);
    dst[r] = s;
  }
  __syncthreads();
  // M[h][c'][c] = sum_{d in head h} W_eq[c'][d] * W_ek[c][d]
  for (int i = tid; i < 256; i += 256) {
    int h = i >> 6, cp = (i >> 3) & 7, c = i & 7;
    float s = 0.f;
    for (int dd = 0; dd < 16; ++dd) s = fmaf(eq[cp*64 + h*16 + dd], ek[c*64 + h*16 + dd], s);
    Mout[i] = s;
  }
  // W_evo[h][c][d'] = sum_{d in head h} W_ev[c][d] * W_o[d][d']
  for (int i = tid; i < 2048; i += 256) {
    int hc = i >> 6, dp = i & 63;
    int h = hc >> 3, c = hc & 7;
    float s = 0.f;
    for (int dd = 0; dd < 16; ++dd) s = fmaf(ev[c*64 + h*16 + dd], Wo[(h*16 + dd)*64 + dp], s);
    Wevo[i] = s;
  }
}

// ---------------- prep: x0, xn, tgt_out ----------------
__global__ __launch_bounds__(256) void k_prep(const float* __restrict__ xc,
                                              float* __restrict__ x0,
                                              float* __restrict__ xn,
                                              float* __restrict__ outT) {
  int g = blockIdx.x * 256 + threadIdx.x;       // 0..32767
  int b = g >> 13, n = g & (NN - 1);
  float v[8];
  float ss = 0.f;
#pragma unroll
  for (int c = 0; c < 8; ++c) {
    float t = xc[((size_t)(b*8 + c) * 2) * NN + n];   // x_c[b][c][0][n]
    v[c] = t; ss = fmaf(t, t, ss);
  }
  float inv = 1.f / (sqrtf(ss) + 1e-12f);
#pragma unroll
  for (int c = 0; c < 8; ++c) {
    x0[(size_t)g*8 + c] = v[c];
    xn[(size_t)g*8 + c] = v[c] * inv;
    outT[(size_t)b*8*NN + (size_t)c*NN + n] = v[c];   // tgt_out
  }
}

// ---------------- top-16 of xn[m]·xn[n] per row ----------------
__device__ __forceinline__ bool betterf(float v1, int i1, float v2, int i2) {
  return (v1 > v2) || (v1 == v2 && i1 < i2);
}

__global__ __launch_bounds__(256, 1) void k_topk(const float* __restrict__ xn,
                                                 int* __restrict__ idxo) {
  __shared__ float sval[4*256];
  __shared__ int   sidx[4*256];
  __shared__ int   swin[4];
  const int tid = threadIdx.x;
  const int rowbase = blockIdx.x * 4;           // global row base (0..32767)
  const int b = rowbase >> 13;
  const float* xnb = xn + (size_t)b * NN * 8;
  const int m0 = rowbase & (NN - 1);

  float q[4][8];
#pragma unroll
  for (int r = 0; r < 4; ++r) {
    const float4* qp = (const float4*)(xnb + (size_t)(m0 + r) * 8);
    float4 a = qp[0], c = qp[1];
    q[r][0]=a.x; q[r][1]=a.y; q[r][2]=a.z; q[r][3]=a.w;
    q[r][4]=c.x; q[r][5]=c.y; q[r][6]=c.z; q[r][7]=c.w;
  }
  float vals[4][32];
#pragma unroll
  for (int j = 0; j < 32; ++j) {
    int n = j * 256 + tid;
    const float4* xp = (const float4*)(xnb + (size_t)n * 8);
    float4 a = xp[0], c = xp[1];
#pragma unroll
    for (int r = 0; r < 4; ++r) {
      float s = a.x * q[r][0];
      s = fmaf(a.y, q[r][1], s); s = fmaf(a.z, q[r][2], s); s = fmaf(a.w, q[r][3], s);
      s = fmaf(c.x, q[r][4], s); s = fmaf(c.y, q[r][5], s);
      s = fmaf(c.z, q[r][6], s); s = fmaf(c.w, q[r][7], s);
      vals[r][j] = s;
    }
  }
  unsigned claimed[4] = {0u, 0u, 0u, 0u};
  float mv[4]; int mi[4];
#pragma unroll
  for (int r = 0; r < 4; ++r) {
    float bm = -1e30f; int bj = 0;
#pragma unroll
    for (int j = 0; j < 32; ++j) {
      if (vals[r][j] > bm) { bm = vals[r][j]; bj = j; }
    }
    mv[r] = bm; mi[r] = bj * 256 + tid;
  }

  for (int k = 0; k < KK; ++k) {
#pragma unroll
    for (int r = 0; r < 4; ++r) { sval[r*256 + tid] = mv[r]; sidx[r*256 + tid] = mi[r]; }
    __syncthreads();
    {
      int w = tid >> 6, lane = tid & 63;      // wave w reduces row w
      float bv = sval[w*256 + lane]; int bi = sidx[w*256 + lane];
#pragma unroll
      for (int i = 1; i < 4; ++i) {
        float v2 = sval[w*256 + lane + 64*i]; int i2 = sidx[w*256 + lane + 64*i];
        if (betterf(v2, i2, bv, bi)) { bv = v2; bi = i2; }
      }
#pragma unroll
      for (int off = 32; off > 0; off >>= 1) {
        float v2 = __shfl_down(bv, off); int i2 = __shfl_down(bi, off);
        if (betterf(v2, i2, bv, bi)) { bv = v2; bi = i2; }
      }
      if (lane == 0) swin[w] = bi;
    }
    __syncthreads();
#pragma unroll
    for (int r = 0; r < 4; ++r) {
      int wn = swin[r];
      if (tid == r) idxo[(size_t)(rowbase + r)*KK + k] = wn;
      if ((wn & 255) == tid) {                // winner thread rescans
        claimed[r] |= (1u << (wn >> 8));
        float bm = -1e30f; int bj = 0;
#pragma unroll
        for (int j = 0; j < 32; ++j) {
          float vv = ((claimed[r] >> j) & 1u) ? -1e30f : vals[r][j];
          if (vv > bm) { bm = vv; bj = j; }
        }
        mv[r] = bm; mi[r] = bj * 256 + tid;
      }
    }
  }
}

// ---------------- attention + W_o + LN1 -> h1 ----------------
__global__ __launch_bounds__(256) void k_attn(const float* __restrict__ x0,
                                              const int* __restrict__ idx,
                                              const float* __restrict__ Wemb,
                                              const float* __restrict__ Mw,
                                              const float* __restrict__ Wevo,
                                              float* __restrict__ h1o) {
  __shared__ float sM[256], sE[512], sV[2048];
  int tid = threadIdx.x;
  for (int i = tid; i < 256;  i += 256) sM[i] = Mw[i];
  for (int i = tid; i < 512;  i += 256) sE[i] = Wemb[i];
  for (int i = tid; i < 2048; i += 256) sV[i] = Wevo[i];
  __syncthreads();
  int l = tid & 63;
  int h = l & 3, kk2 = l >> 2;                  // 4 heads x 16 neighbors
  int wid = blockIdx.x * 4 + (tid >> 6);
  for (int it = 0; it < 4; ++it) {
    int g = wid * 4 + it;
    int b = g >> 13;
    const float4* xq = (const float4*)(x0 + (size_t)g * 8);
    float4 a0 = xq[0], a1 = xq[1];
    float x0q[8] = {a0.x, a0.y, a0.z, a0.w, a1.x, a1.y, a1.z, a1.w};
    int nk = idx[(size_t)g*KK + kk2];
    const float4* xs = (const float4*)(x0 + ((size_t)(b*NN) + nk) * 8);
    float4 s0 = xs[0], s1v = xs[1];
    float sx[8] = {s0.x, s0.y, s0.z, s0.w, s1v.x, s1v.y, s1v.z, s1v.w};
    // qe[c] = sum_c' x0q[c'] * M[h][c'][c]
    float qe[8];
#pragma unroll
    for (int c = 0; c < 8; ++c) {
      float s = 0.f;
#pragma unroll
      for (int c2 = 0; c2 < 8; ++c2) s = fmaf(x0q[c2], sM[h*64 + c2*8 + c], s);
      qe[c] = s;
    }
    float att = 0.f;
#pragma unroll
    for (int c = 0; c < 8; ++c) att = fmaf(sx[c], qe[c], att);
    att *= 0.25f;                               // 1/sqrt(DH)
    // softmax over the 16-lane group (same h, stride 4)
    float mx = att;
#pragma unroll
    for (int off = 4; off <= 32; off <<= 1) mx = fmaxf(mx, __shfl_xor(mx, off));
    float e = __expf(att - mx);
    float sum = e;
#pragma unroll
    for (int off = 4; off <= 32; off <<= 1) sum += __shfl_xor(sum, off);
    float p = e / sum;
    // ps[h][c] = sum_k p_k * sx[k][c]
    float ps[8];
#pragma unroll
    for (int c = 0; c < 8; ++c) ps[c] = p * sx[c];
#pragma unroll
    for (int off = 4; off <= 32; off <<= 1) {
#pragma unroll
      for (int c = 0; c < 8; ++c) ps[c] += __shfl_xor(ps[c], off);
    }
    // r1[d=l] = te[d] + sum_{h,c} ps[h][c] * W_evo[h][c][d]
    float r1 = 0.f;
#pragma unroll
    for (int c = 0; c < 8; ++c) {
      float pc = ps[c];
#pragma unroll
      for (int hh = 0; hh < 4; ++hh) {
        float v = __shfl(pc, hh);               // lane hh holds ps[hh][c]
        r1 = fmaf(v, sV[(hh*8 + c)*64 + l], r1);
      }
    }
#pragma unroll
    for (int c = 0; c < 8; ++c) r1 = fmaf(x0q[c], sE[c*64 + l], r1);
    // LayerNorm over 64 lanes
    float s1 = r1, s2 = r1 * r1;
#pragma unroll
    for (int off = 1; off <= 32; off <<= 1) { s1 += __shfl_xor(s1, off); s2 += __shfl_xor(s2, off); }
    float m = s1 * (1.f/64.f), var = s2 * (1.f/64.f) - m*m;
    float h1v = (r1 - m) * rsqrtf(var + 1e-5f);
    h1o[(size_t)g*DD + l] = h1v;
  }
}

// ---------------- FF (relu MLP) + LN2 + W_out -> sq_c ----------------
__global__ __launch_bounds__(256) void k_ff(const float* __restrict__ h1,
                                            const float* __restrict__ W1,
                                            const float* __restrict__ W2,
                                            const float* __restrict__ Wout,
                                            float* __restrict__ outp) {
  __shared__ float  h1t[16*64];       // 4 KB
  __shared__ __half uh[16*260];       // 8.1 KB (row pad 260 halves)
  __shared__ __half w2h[256*66];      // 33 KB  (row pad 66 halves)
  __shared__ float  swout[512];       // 2 KB
  __shared__ float  red[16*16*2];     // 2 KB
  __shared__ float  red2[16*16*8];    // 8 KB
  int tid = threadIdx.x;
  int g0 = blockIdx.x * 16;
  for (int i = tid; i < 1024; i += 256) h1t[i] = h1[(size_t)g0*DD + i];
  {
    int f = tid;                       // stage W2 as fp16
#pragma unroll
    for (int i = 0; i < 64; ++i) w2h[f*66 + i] = __float2half(W2[f*64 + i]);
  }
  for (int i = tid; i < 512; i += 256) swout[i] = Wout[i];
  __syncthreads();
  // phase 1: thread <-> f, W1 column in regs
  {
    float w1[64];
#pragma unroll
    for (int d2 = 0; d2 < 64; ++d2) w1[d2] = W1[d2*256 + tid];
    for (int t = 0; t < 16; ++t) {
      float acc = 0.f;
#pragma unroll
      for (int d4 = 0; d4 < 16; ++d4) {
        float4 hv = *(const float4*)&h1t[t*64 + d4*4];
        acc = fmaf(hv.x, w1[d4*4+0], acc);
        acc = fmaf(hv.y, w1[d4*4+1], acc);
        acc = fmaf(hv.z, w1[d4*4+2], acc);
        acc = fmaf(hv.w, w1[d4*4+3], acc);
      }
      uh[t*260 + tid] = __float2half(fmaxf(acc, 0.f));
    }
  }
  __syncthreads();
  // phase 2: thread <-> (t, d-quad)
  int t = tid >> 4, dq = tid & 15, d0 = dq * 4;
  float acc[4];
#pragma unroll
  for (int j = 0; j < 4; ++j) acc[j] = h1t[t*64 + d0 + j];   // residual h1
#pragma unroll 4
  for (int f = 0; f < 256; ++f) {
    float uf = __half2float(uh[t*260 + f]);
#pragma unroll
    for (int j = 0; j < 4; ++j)
      acc[j] = fmaf(uf, __half2float(w2h[f*66 + d0 + j]), acc[j]);
  }
  float s1 = acc[0] + acc[1] + acc[2] + acc[3];
  float s2 = acc[0]*acc[0] + acc[1]*acc[1] + acc[2]*acc[2] + acc[3]*acc[3];
  red[(t*16 + dq)*2 + 0] = s1; red[(t*16 + dq)*2 + 1] = s2;
  __syncthreads();
  float S1 = 0.f, S2 = 0.f;
#pragma unroll
  for (int i = 0; i < 16; ++i) { S1 += red[(t*16 + i)*2]; S2 += red[(t*16 + i)*2 + 1]; }
  float m = S1 * (1.f/64.f), var = S2 * (1.f/64.f) - m*m;
  float rs = rsqrtf(var + 1e-5f);
  float oc[8] = {0,0,0,0,0,0,0,0};
#pragma unroll
  for (int j = 0; j < 4; ++j) {
    float h2 = (acc[j] - m) * rs;
#pragma unroll
    for (int c = 0; c < 8; ++c) oc[c] = fmaf(h2, swout[(d0 + j)*8 + c], oc[c]);
  }
#pragma unroll
  for (int c = 0; c < 8; ++c) red2[(t*16 + dq)*8 + c] = oc[c];
  __syncthreads();
  if (dq < 8) {
    float s = 0.f;
#pragma unroll
    for (int grp = 0; grp < 16; ++grp) s += red2[(t*16 + grp)*8 + dq];
    outp[(size_t)(g0 + t)*8 + dq] = s;
  }
}

// ---------------- launch ----------------
extern "C" void kernel_launch(void* const* d_in, const int* in_sizes, int n_in,
                              void* d_out, int out_size, void* d_ws, size_t ws_size,
                              hipStream_t stream) {
  const float* xc   = (const float*)d_in[0];
  const float* Wemb = (const float*)d_in[1];
  const float* Wqkv = (const float*)d_in[2];
  const float* Wo   = (const float*)d_in[3];
  const float* W1   = (const float*)d_in[4];
  const float* W2   = (const float*)d_in[5];
  const float* Wout = (const float*)d_in[6];
  float* out = (float*)d_out;
  float* fw  = (float*)d_ws;
  float* x0  = fw + WS_X0;
  float* xn  = fw + WS_XN;
  int*   idx = (int*)(fw + WS_IDX);
  float* Mw  = fw + WS_M;
  float* Wevo= fw + WS_EVO;
  float* h1  = fw + WS_H1;

  hipLaunchKernelGGL(k_fusew, dim3(1),       dim3(256), 0, stream, Wemb, Wqkv, Wo, Mw, Wevo);
  hipLaunchKernelGGL(k_prep,  dim3(NT/256),  dim3(256), 0, stream, xc, x0, xn, out + (size_t)NT*CCH);
  hipLaunchKernelGGL(k_topk,  dim3(NT/4),    dim3(256), 0, stream, xn, idx);
  hipLaunchKernelGGL(k_attn,  dim3(2048),    dim3(256), 0, stream, x0, idx, Wemb, Mw, Wevo, h1);
  hipLaunchKernelGGL(k_ff,    dim3(2048),    dim3(256), 0, stream, h1, W1, W2, Wout, out);
}

// Round 2
// 315.431 us; speedup vs baseline: 2.4942x; 2.4942x over previous
//
#include <hip/hip_runtime.h>
#include <hip/hip_fp16.h>

#define BSZ 4
#define CCH 8
#define NN  8192
#define KK  16
#define DD  64
#define HHD 4
#define FFD 256
#define NT  (BSZ*NN)   // 32768 tokens

// ---------------- workspace layout (in floats) ----------------
#define WS_X0   0
#define WS_XN   (WS_X0 + NT*CCH)          // 262144
#define WS_IDX  (WS_XN + NT*CCH)          // int region, NT*KK ints
#define WS_M    (WS_IDX + NT*KK)          // 256 floats
#define WS_EVO  (WS_M + 256)              // 2048 floats
#define WS_H1   (WS_EVO + 2048)           // NT*64 floats

// ---------------- weight fusion (tiny, 1 block) ----------------
__global__ __launch_bounds__(256) void k_fusew(const float* __restrict__ Wemb,
                                               const float* __restrict__ Wqkv,
                                               const float* __restrict__ Wo,
                                               float* __restrict__ Mout,
                                               float* __restrict__ Wevo) {
  __shared__ float eq[512], ek[512], ev[512];
  int tid = threadIdx.x;
  for (int i = tid; i < 1536; i += 256) {
    int w = i >> 9;           // 0=q,1=k,2=v
    int r = i & 511;          // c*64+d
    int c = r >> 6, d = r & 63;
    float s = 0.f;
    for (int e = 0; e < 64; ++e) s = fmaf(Wemb[c*64+e], Wqkv[w*4096 + e*64 + d], s);
    float* dst = (w == 0) ? eq : ((w == 1) ? ek : ev);
    dst[r] = s;
  }
  __syncthreads();
  // M[h][c'][c] = sum_{d in head h} W_eq[c'][d] * W_ek[c][d]
  for (int i = tid; i < 256; i += 256) {
    int h = i >> 6, cp = (i >> 3) & 7, c = i & 7;
    float s = 0.f;
    for (int dd = 0; dd < 16; ++dd) s = fmaf(eq[cp*64 + h*16 + dd], ek[c*64 + h*16 + dd], s);
    Mout[i] = s;
  }
  // W_evo[h][c][d'] = sum_{d in head h} W_ev[c][d] * W_o[d][d']
  for (int i = tid; i < 2048; i += 256) {
    int hc = i >> 6, dp = i & 63;
    int h = hc >> 3, c = hc & 7;
    float s = 0.f;
    for (int dd = 0; dd < 16; ++dd) s = fmaf(ev[c*64 + h*16 + dd], Wo[(h*16 + dd)*64 + dp], s);
    Wevo[i] = s;
  }
}

// ---------------- prep: x0, xn, tgt_out ----------------
__global__ __launch_bounds__(256) void k_prep(const float* __restrict__ xc,
                                              float* __restrict__ x0,
                                              float* __restrict__ xn,
                                              float* __restrict__ outT) {
  int g = blockIdx.x * 256 + threadIdx.x;       // 0..32767
  int b = g >> 13, n = g & (NN - 1);
  float v[8];
  float ss = 0.f;
#pragma unroll
  for (int c = 0; c < 8; ++c) {
    float t = xc[((size_t)(b*8 + c) * 2) * NN + n];   // x_c[b][c][0][n]
    v[c] = t; ss = fmaf(t, t, ss);
  }
  float inv = 1.f / (sqrtf(ss) + 1e-12f);
#pragma unroll
  for (int c = 0; c < 8; ++c) {
    x0[(size_t)g*8 + c] = v[c];
    xn[(size_t)g*8 + c] = v[c] * inv;
    outT[(size_t)b*8*NN + (size_t)c*NN + n] = v[c];   // tgt_out
  }
}

// ---------------- top-16 of xn[m]·xn[n] per row: 2-pass histogram select ----------------
#define TPK_R   8       // rows per block
#define TPK_NB  512     // histogram bins over [-1, 1]
#define TPK_CAP 192     // candidate capacity per row

__global__ __launch_bounds__(256, 2) void k_topk(const float* __restrict__ xn,
                                                 int* __restrict__ idxo) {
  __shared__ int   hist[TPK_R][TPK_NB];     // 16 KB
  __shared__ float scv[TPK_R][TPK_CAP];     // 6 KB
  __shared__ int   sci[TPK_R][TPK_CAP];     // 6 KB
  __shared__ int   sB[TPK_R];
  __shared__ int   scnt[TPK_R];
  const int tid = threadIdx.x;
  const int rowbase = blockIdx.x * TPK_R;   // 0..32767
  const int b = rowbase >> 13;
  const int m0 = rowbase & (NN - 1);
  const float* xnb = xn + (size_t)b * NN * 8;

  // q-vectors for the block's 8 rows, in registers (64 floats)
  float qv[TPK_R][8];
#pragma unroll
  for (int r = 0; r < TPK_R; ++r) {
    const float4* qp = (const float4*)(xnb + (size_t)(m0 + r) * 8);
    float4 a = qp[0], c = qp[1];
    qv[r][0]=a.x; qv[r][1]=a.y; qv[r][2]=a.z; qv[r][3]=a.w;
    qv[r][4]=c.x; qv[r][5]=c.y; qv[r][6]=c.z; qv[r][7]=c.w;
  }
  for (int i = tid; i < TPK_R*TPK_NB; i += 256) ((int*)hist)[i] = 0;
  if (tid < TPK_R) scnt[tid] = 0;
  __syncthreads();

  // pass 1: histogram
  for (int j = tid; j < NN; j += 256) {
    const float4* xp = (const float4*)(xnb + (size_t)j * 8);
    float4 a = xp[0], c = xp[1];
#pragma unroll
    for (int r = 0; r < TPK_R; ++r) {
      float v = a.x * qv[r][0];
      v = fmaf(a.y, qv[r][1], v); v = fmaf(a.z, qv[r][2], v); v = fmaf(a.w, qv[r][3], v);
      v = fmaf(c.x, qv[r][4], v); v = fmaf(c.y, qv[r][5], v);
      v = fmaf(c.z, qv[r][6], v); v = fmaf(c.w, qv[r][7], v);
      int bb = (int)((v + 1.0f) * 256.0f);
      bb = bb < 0 ? 0 : (bb > (TPK_NB-1) ? (TPK_NB-1) : bb);
      atomicAdd(&hist[r][bb], 1);
    }
  }
  __syncthreads();

  // threshold bin per row: first bin from the top with cumulative >= 16
  if (tid < TPK_R) {
    int cum = 0, bin = TPK_NB - 1;
    for (;;) {
      cum += hist[tid][bin];
      if (cum >= KK || bin == 0) break;
      --bin;
    }
    sB[tid] = bin;
  }
  __syncthreads();

  // pass 2: recompute dots (identical fmaf chain -> identical bits), collect candidates
  for (int j = tid; j < NN; j += 256) {
    const float4* xp = (const float4*)(xnb + (size_t)j * 8);
    float4 a = xp[0], c = xp[1];
#pragma unroll
    for (int r = 0; r < TPK_R; ++r) {
      float v = a.x * qv[r][0];
      v = fmaf(a.y, qv[r][1], v); v = fmaf(a.z, qv[r][2], v); v = fmaf(a.w, qv[r][3], v);
      v = fmaf(c.x, qv[r][4], v); v = fmaf(c.y, qv[r][5], v);
      v = fmaf(c.z, qv[r][6], v); v = fmaf(c.w, qv[r][7], v);
      int bb = (int)((v + 1.0f) * 256.0f);
      bb = bb < 0 ? 0 : (bb > (TPK_NB-1) ? (TPK_NB-1) : bb);
      if (bb >= sB[r]) {
        int p = atomicAdd(&scnt[r], 1);
        if (p < TPK_CAP) { scv[r][p] = v; sci[r][p] = j; }
      }
    }
  }
  __syncthreads();

  // rank-based exact top-16 among candidates: rank = #better by (v desc, idx asc)
  {
    int r = tid >> 5, s0 = tid & 31;   // 32 threads per row
    int n = scnt[r]; if (n > TPK_CAP) n = TPK_CAP;
    for (int s = s0; s < n; s += 32) {
      float v = scv[r][s]; int id = sci[r][s];
      int rank = 0;
      for (int t2 = 0; t2 < n; ++t2) {
        float vo = scv[r][t2]; int io = sci[r][t2];
        rank += (vo > v || (vo == v && io < id)) ? 1 : 0;
      }
      if (rank < KK) idxo[(size_t)(rowbase + r)*KK + rank] = id;
    }
  }
}

// ---------------- attention + W_o + LN1 -> h1 ----------------
__global__ __launch_bounds__(256) void k_attn(const float* __restrict__ x0,
                                              const int* __restrict__ idx,
                                              const float* __restrict__ Wemb,
                                              const float* __restrict__ Mw,
                                              const float* __restrict__ Wevo,
                                              float* __restrict__ h1o) {
  __shared__ float sM[256], sE[512], sV[2048];
  int tid = threadIdx.x;
  for (int i = tid; i < 256;  i += 256) sM[i] = Mw[i];
  for (int i = tid; i < 512;  i += 256) sE[i] = Wemb[i];
  for (int i = tid; i < 2048; i += 256) sV[i] = Wevo[i];
  __syncthreads();
  int l = tid & 63;
  int h = l & 3, kk2 = l >> 2;                  // 4 heads x 16 neighbors
  int wid = blockIdx.x * 4 + (tid >> 6);
  for (int it = 0; it < 4; ++it) {
    int g = wid * 4 + it;
    int b = g >> 13;
    const float4* xq = (const float4*)(x0 + (size_t)g * 8);
    float4 a0 = xq[0], a1 = xq[1];
    float x0q[8] = {a0.x, a0.y, a0.z, a0.w, a1.x, a1.y, a1.z, a1.w};
    int nk = idx[(size_t)g*KK + kk2];
    const float4* xs = (const float4*)(x0 + ((size_t)(b*NN) + nk) * 8);
    float4 s0 = xs[0], s1v = xs[1];
    float sx[8] = {s0.x, s0.y, s0.z, s0.w, s1v.x, s1v.y, s1v.z, s1v.w};
    // qe[c] = sum_c' x0q[c'] * M[h][c'][c]
    float qe[8];
#pragma unroll
    for (int c = 0; c < 8; ++c) {
      float s = 0.f;
#pragma unroll
      for (int c2 = 0; c2 < 8; ++c2) s = fmaf(x0q[c2], sM[h*64 + c2*8 + c], s);
      qe[c] = s;
    }
    float att = 0.f;
#pragma unroll
    for (int c = 0; c < 8; ++c) att = fmaf(sx[c], qe[c], att);
    att *= 0.25f;                               // 1/sqrt(DH)
    // softmax over the 16-lane group (same h, stride 4)
    float mx = att;
#pragma unroll
    for (int off = 4; off <= 32; off <<= 1) mx = fmaxf(mx, __shfl_xor(mx, off));
    float e = __expf(att - mx);
    float sum = e;
#pragma unroll
    for (int off = 4; off <= 32; off <<= 1) sum += __shfl_xor(sum, off);
    float p = e / sum;
    // ps[h][c] = sum_k p_k * sx[k][c]
    float ps[8];
#pragma unroll
    for (int c = 0; c < 8; ++c) ps[c] = p * sx[c];
#pragma unroll
    for (int off = 4; off <= 32; off <<= 1) {
#pragma unroll
      for (int c = 0; c < 8; ++c) ps[c] += __shfl_xor(ps[c], off);
    }
    // r1[d=l] = te[d] + sum_{h,c} ps[h][c] * W_evo[h][c][d]
    float r1 = 0.f;
#pragma unroll
    for (int c = 0; c < 8; ++c) {
      float pc = ps[c];
#pragma unroll
      for (int hh = 0; hh < 4; ++hh) {
        float v = __shfl(pc, hh);               // lane hh holds ps[hh][c]
        r1 = fmaf(v, sV[(hh*8 + c)*64 + l], r1);
      }
    }
#pragma unroll
    for (int c = 0; c < 8; ++c) r1 = fmaf(x0q[c], sE[c*64 + l], r1);
    // LayerNorm over 64 lanes
    float s1 = r1, s2 = r1 * r1;
#pragma unroll
    for (int off = 1; off <= 32; off <<= 1) { s1 += __shfl_xor(s1, off); s2 += __shfl_xor(s2, off); }
    float m = s1 * (1.f/64.f), var = s2 * (1.f/64.f) - m*m;
    float h1v = (r1 - m) * rsqrtf(var + 1e-5f);
    h1o[(size_t)g*DD + l] = h1v;
  }
}

// ---------------- FF (relu MLP) + LN2 + W_out -> sq_c ----------------
__global__ __launch_bounds__(256) void k_ff(const float* __restrict__ h1,
                                            const float* __restrict__ W1,
                                            const float* __restrict__ W2,
                                            const float* __restrict__ Wout,
                                            float* __restrict__ outp) {
  __shared__ float  h1t[16*64];       // 4 KB
  __shared__ __half uh[16*260];       // 8.1 KB (row pad 260 halves)
  __shared__ __half w2h[256*66];      // 33 KB  (row pad 66 halves)
  __shared__ float  swout[512];       // 2 KB
  __shared__ float  red[16*16*2];     // 2 KB
  __shared__ float  red2[16*16*8];    // 8 KB
  int tid = threadIdx.x;
  int g0 = blockIdx.x * 16;
  for (int i = tid; i < 1024; i += 256) h1t[i] = h1[(size_t)g0*DD + i];
  {
    int f = tid;                       // stage W2 as fp16
#pragma unroll
    for (int i = 0; i < 64; ++i) w2h[f*66 + i] = __float2half(W2[f*64 + i]);
  }
  for (int i = tid; i < 512; i += 256) swout[i] = Wout[i];
  __syncthreads();
  // phase 1: thread <-> f, W1 column in regs
  {
    float w1[64];
#pragma unroll
    for (int d2 = 0; d2 < 64; ++d2) w1[d2] = W1[d2*256 + tid];
    for (int t = 0; t < 16; ++t) {
      float acc = 0.f;
#pragma unroll
      for (int d4 = 0; d4 < 16; ++d4) {
        float4 hv = *(const float4*)&h1t[t*64 + d4*4];
        acc = fmaf(hv.x, w1[d4*4+0], acc);
        acc = fmaf(hv.y, w1[d4*4+1], acc);
        acc = fmaf(hv.z, w1[d4*4+2], acc);
        acc = fmaf(hv.w, w1[d4*4+3], acc);
      }
      uh[t*260 + tid] = __float2half(fmaxf(acc, 0.f));
    }
  }
  __syncthreads();
  // phase 2: thread <-> (t, d-quad)
  int t = tid >> 4, dq = tid & 15, d0 = dq * 4;
  float acc[4];
#pragma unroll
  for (int j = 0; j < 4; ++j) acc[j] = h1t[t*64 + d0 + j];   // residual h1
#pragma unroll 4
  for (int f = 0; f < 256; ++f) {
    float uf = __half2float(uh[t*260 + f]);
#pragma unroll
    for (int j = 0; j < 4; ++j)
      acc[j] = fmaf(uf, __half2float(w2h[f*66 + d0 + j]), acc[j]);
  }
  float s1 = acc[0] + acc[1] + acc[2] + acc[3];
  float s2 = acc[0]*acc[0] + acc[1]*acc[1] + acc[2]*acc[2] + acc[3]*acc[3];
  red[(t*16 + dq)*2 + 0] = s1; red[(t*16 + dq)*2 + 1] = s2;
  __syncthreads();
  float S1 = 0.f, S2 = 0.f;
#pragma unroll
  for (int i = 0; i < 16; ++i) { S1 += red[(t*16 + i)*2]; S2 += red[(t*16 + i)*2 + 1]; }
  float m = S1 * (1.f/64.f), var = S2 * (1.f/64.f) - m*m;
  float rs = rsqrtf(var + 1e-5f);
  float oc[8] = {0,0,0,0,0,0,0,0};
#pragma unroll
  for (int j = 0; j < 4; ++j) {
    float h2 = (acc[j] - m) * rs;
#pragma unroll
    for (int c = 0; c < 8; ++c) oc[c] = fmaf(h2, swout[(d0 + j)*8 + c], oc[c]);
  }
#pragma unroll
  for (int c = 0; c < 8; ++c) red2[(t*16 + dq)*8 + c] = oc[c];
  __syncthreads();
  if (dq < 8) {
    float s = 0.f;
#pragma unroll
    for (int grp = 0; grp < 16; ++grp) s += red2[(t*16 + grp)*8 + dq];
    outp[(size_t)(g0 + t)*8 + dq] = s;
  }
}

// ---------------- launch ----------------
extern "C" void kernel_launch(void* const* d_in, const int* in_sizes, int n_in,
                              void* d_out, int out_size, void* d_ws, size_t ws_size,
                              hipStream_t stream) {
  const float* xc   = (const float*)d_in[0];
  const float* Wemb = (const float*)d_in[1];
  const float* Wqkv = (const float*)d_in[2];
  const float* Wo   = (const float*)d_in[3];
  const float* W1   = (const float*)d_in[4];
  const float* W2   = (const float*)d_in[5];
  const float* Wout = (const float*)d_in[6];
  float* out = (float*)d_out;
  float* fw  = (float*)d_ws;
  float* x0  = fw + WS_X0;
  float* xn  = fw + WS_XN;
  int*   idx = (int*)(fw + WS_IDX);
  float* Mw  = fw + WS_M;
  float* Wevo= fw + WS_EVO;
  float* h1  = fw + WS_H1;

  hipLaunchKernelGGL(k_fusew, dim3(1),          dim3(256), 0, stream, Wemb, Wqkv, Wo, Mw, Wevo);
  hipLaunchKernelGGL(k_prep,  dim3(NT/256),     dim3(256), 0, stream, xc, x0, xn, out + (size_t)NT*CCH);
  hipLaunchKernelGGL(k_topk,  dim3(NT/TPK_R),   dim3(256), 0, stream, xn, idx);
  hipLaunchKernelGGL(k_attn,  dim3(2048),       dim3(256), 0, stream, x0, idx, Wemb, Mw, Wevo, h1);
  hipLaunchKernelGGL(k_ff,    dim3(2048),       dim3(256), 0, stream, h1, W1, W2, Wout, out);
}